// Round 1
// 412.663 us; speedup vs baseline: 1.0034x; 1.0034x over previous
//
#include <hip/hip_runtime.h>

// LinearAttention bf16-MFMA pipeline. 256x256 GEMM, BK=64, 8-phase schedule.
// R10 change vs R9: register-pipelined phases. Every phase's MFMA block now
// consumes fragments ds_read one phase EARLIER (frag double-buffer), so the
// LDS-read service time overlaps the MFMA-pipe time instead of serializing
// (R9 phases ~1950 cy vs 621-cy MFMA floor; MfmaUtil 27%). Counted vmcnt(2)
// drains moved to ph3/ph7 so the buffer-publish barrier lands one phase before
// the first read of that buffer -> ph1/ph5 pipeline too. One barrier per phase
// (8/iter, was 16); each phase tail = {s_waitcnt lgkm/vm; sched_barrier(0);
// s_barrier} which (a) closes the ds_read-in-flight-past-barrier race and
// (b) pins nothing inside the phase (reads/MFMAs free to interleave).
//
// B=8, S=4096, D=1024, F=1024.
// out[b,f,s] = sum_g ctxRaw[b,f,g] * Qs[b,s,g]
//   ctxRaw = K^T V (unscaled);  Qs = (relu(x@Wq)+1)/(den+eps)
//   den[b,g] = sum_s K[b,s,g];  K = relu(x@Wk)+1;  V = x@Wv
// All GEMMs: C[M][N] = sum_k A[M][K] * Bt[N][K]  (NT, both row-major bf16).
//
// Ledger (iter i, t=2i; buf0=even tiles, buf1=odd; halves l/h = rows 0-127/128-255):
//  window p = between s_barrier(p-1) and s_barrier(p). Per window:
//   ph1: MM(a03,b0 buf0.kk0) | prefetch a47<-buf0.A kk0 | stage (t+1).Al->buf1.A
//   ph2: MM(a47,b0)          | prefetch a03<-buf0.A kk1, b1<-buf0.B kk1 | stage (t+1).Ah->buf1.A
//   ph3: MM(a03,b1)          | prefetch a47<-buf0.A kk1 | stage (t+2).Bl->buf0.B | vmcnt(2)
//   ph4: MM(a47,b1)          | prefetch a03<-buf1.A kk0, b0<-buf1.B kk0 | stage (t+2).Bh->buf0.B
//   ph5-8: mirror on buf1, stages (t+2).Al/Ah->buf0.A, (t+3).Bl/Bh->buf1.B, vmcnt(2) at ph7
//  vmcnt(2)@ph3 drains (t+1).B[prev ph7/8] + (t+1).A[ph1/2] -> buf1 published at B(ph3),
//   one window before ph4's buf1 prefetch. vmcnt(2)@ph7 drains all (t+2) -> buf0 published
//   at B(ph7), one window before ph8's buf0 prefetch (next tile's ph1 frags).
//  Hazard audit (per window: read regions vs stage-issue regions vs stage-arrival
//   regions): disjoint in all 8 windows; every region's last read is lgkm-drained
//   before the barrier that precedes its overwriting stage-issue.
//  Prologue: t0.B, t0.A, t1.B (12 loads); vmcnt(4) = t0 landed; then pre-read
//   ph1 frags (a03,b0 <- buf0 kk0).

#define EPSF 1e-6f

constexpr int Bb = 8;
constexpr int Ss = 4096;
constexpr int Dd = 1024;
constexpr int Ff = 1024;

typedef __attribute__((ext_vector_type(8))) short   bf16x8;
typedef __attribute__((ext_vector_type(8))) unsigned short u16x8;
typedef __attribute__((ext_vector_type(4))) float   f32x4;

// explicit LDS (addrspace 3) pointer types
typedef __attribute__((address_space(3))) unsigned char lds_u8;
typedef __attribute__((address_space(3))) const bf16x8  lds_cvec;

static __device__ __forceinline__ unsigned short f2bf(float f) {
    union { float f; unsigned int u; } v; v.f = f;
    unsigned int r = (v.u + 0x7fffu + ((v.u >> 16) & 1u)) >> 16;
    return (unsigned short)r;
}
static __device__ __forceinline__ float bf2f(unsigned short u) {
    union { unsigned int u; float f; } v; v.u = ((unsigned int)u) << 16;
    return v.f;
}

static __device__ __forceinline__ void gld_lds16(const void* g, lds_u8* l) {
    __builtin_amdgcn_global_load_lds(
        (const __attribute__((address_space(1))) unsigned int*)g,
        (__attribute__((address_space(3))) unsigned int*)l,
        16, 0, 0);
}

// ---------------------------------------------------------------------------
__global__ void cvt_x_kernel(const float* __restrict__ x, unsigned short* __restrict__ xb, int n4)
{
    int i = blockIdx.x * blockDim.x + threadIdx.x;
    if (i >= n4) return;
    float4 v = *(const float4*)&x[(size_t)i * 4];
    ushort4 o;
    o.x = f2bf(v.x); o.y = f2bf(v.y); o.z = f2bf(v.z); o.w = f2bf(v.w);
    *(ushort4*)&xb[(size_t)i * 4] = o;
}

// W[d][f] fp32 -> WT[f][d] bf16 (x3 weights)
__global__ void cvt_wT_kernel(const float* __restrict__ Wq,
                              const float* __restrict__ Wk,
                              const float* __restrict__ Wv,
                              unsigned short* __restrict__ WT)
{
    const int z = blockIdx.z;
    const float* __restrict__ W = (z == 0) ? Wq : (z == 1 ? Wk : Wv);
    unsigned short* __restrict__ dst = WT + (size_t)z * Dd * Ff;

    __shared__ float tile[32][33];
    const int tid = threadIdx.x;
    const int d0 = blockIdx.y * 32, f0 = blockIdx.x * 32;
    const int c = tid & 31, r8 = tid >> 5;
#pragma unroll
    for (int p = 0; p < 4; ++p) {
        int r = p * 8 + r8;
        tile[r][c] = W[(size_t)(d0 + r) * Ff + f0 + c];
    }
    __syncthreads();
#pragma unroll
    for (int p = 0; p < 4; ++p) {
        int r = p * 8 + r8;
        dst[(size_t)(f0 + r) * Dd + d0 + c] = f2bf(tile[c][r]);
    }
}

// den[b][f] = sum_s KbT[b][f][s]
__global__ void den_kernel(const unsigned short* __restrict__ KbT, float* __restrict__ den)
{
    const int tid = threadIdx.x;
    const int w = tid >> 6, lane = tid & 63;
    const int f = blockIdx.x * 4 + w;
    const int b = blockIdx.y;
    const unsigned short* __restrict__ row = KbT + ((size_t)b * Ff + f) * Ss;
    float s = 0.f;
#pragma unroll
    for (int it = 0; it < Ss / 512; ++it) {
        u16x8 v = *(const u16x8*)&row[it * 512 + lane * 8];
#pragma unroll
        for (int j = 0; j < 8; ++j) s += bf2f(v[j]);
    }
#pragma unroll
    for (int off = 32; off > 0; off >>= 1) s += __shfl_down(s, off, 64);
    if (lane == 0) den[(size_t)b * Ff + f] = s;
}

// ctx[b] = p[2b] + p[2b+1]  (bf16 split-K partials)
__global__ void add_ctx_kernel(const unsigned short* __restrict__ p,
                               unsigned short* __restrict__ c)
{
    const int b = blockIdx.y;
    const size_t i8 = ((size_t)blockIdx.x * 256 + threadIdx.x) * 8;
    const u16x8 a0 = *(const u16x8*)(p + (size_t)(2 * b) * Ff * Ff + i8);
    const u16x8 a1 = *(const u16x8*)(p + (size_t)(2 * b + 1) * Ff * Ff + i8);
    u16x8 o;
#pragma unroll
    for (int j = 0; j < 8; ++j) o[j] = f2bf(bf2f(a0[j]) + bf2f(a1[j]));
    *(u16x8*)(c + (size_t)b * Ff * Ff + i8) = o;
}

// ---------------------------------------------------------------------------
// 256x256 NT bf16 MFMA GEMM, 512 threads, 8 waves (2M x 4N), BK=64, 8-phase,
// register-pipelined (frags read one phase ahead), 1 barrier/phase.
// LDS: buf0.A@0 buf0.B@32K buf1.A@64K buf1.B@96K; each [256 rows][128B],
// 16B-chunk XOR-swizzle key=(row&7). MFMA swapped operands (C^T frags).
template<int ACT, int SCALE, int OUT_BF16, int SPLITK2>
__global__ __launch_bounds__(512, 2)
void gemm8(const unsigned short* __restrict__ A,
           const unsigned short* __restrict__ Bt,
           void* __restrict__ Cout,
           const float* __restrict__ den,
           int lda, int ldb, int ldc, int Kdim,
           size_t strideA, size_t strideB, size_t strideC)
{
    __shared__ __align__(16) unsigned char smem_[131072];
    lds_u8* const smem = (lds_u8*)smem_;

    // ---- XCD-aware bijective block swizzle (total blocks % 8 == 0 always)
    const int gx = gridDim.x, gxy = gx * gridDim.y;
    int flat = blockIdx.z * gxy + blockIdx.y * gx + blockIdx.x;
    const int nwg = gxy * gridDim.z;
    const int cpx = nwg >> 3;
    flat = (flat & 7) * cpx + (flat >> 3);
    const int z = flat / gxy;
    const int rem = flat - z * gxy;
    const int by = rem / gx;
    const int bx = rem - by * gx;

    const int zb   = SPLITK2 ? (z >> 1) : z;
    const int koff = SPLITK2 ? ((z & 1) * Kdim) : 0;

    const unsigned short* __restrict__ Ag  = A  + strideA * zb + koff;
    const unsigned short* __restrict__ Bg  = Bt + strideB * zb + koff;
    const float* __restrict__ denb = SCALE ? (den + (size_t)zb * Ff) : nullptr;

    const int bm = by * 256;
    const int bn = bx * 256;

    const int tid  = threadIdx.x;
    const int wv   = tid >> 6, lane = tid & 63;
    const int wm   = wv >> 2, wn = wv & 3;        // 2 x 4 wave grid
    const int lm   = lane & 15;
    const int kg16 = (lane >> 4) << 4;            // k-group byte offset
    const int swz  = (lm & 7) << 4;               // read-side XOR key (row&7)
    const int kbs  = (((tid & 7) ^ ((tid >> 3) & 7)) << 4);  // stage src chunk
    const int srow = tid >> 3;                    // stage row within 64-row q-block

    f32x4 acc[8][4];
#pragma unroll
    for (int i = 0; i < 8; ++i)
#pragma unroll
        for (int j = 0; j < 4; ++j) acc[i][j] = (f32x4){0.f, 0.f, 0.f, 0.f};

    lds_u8* const A0 = smem;
    lds_u8* const B0 = smem + 32768;
    lds_u8* const A1 = smem + 65536;
    lds_u8* const B1 = smem + 98304;

    // stage one half-tile (16KB, 2 gld_lds16/thread) of K-tile ts.
    // m: 0=A 1=B; buf: 0/1; h: 0=rows0-127 1=rows128-255.
    auto STAGE = [&](int ts, int m, int buf, int h) {
        const unsigned short* gb = m ? Bg : Ag;
        const int ld = m ? ldb : lda;
        const int off0 = m ? bn : bm;
        lds_u8* lb = smem + buf * 65536 + m * 32768 + h * 16384 + wv * 1024;
#pragma unroll
        for (int q = 0; q < 2; ++q) {
            int row = h * 128 + q * 64 + srow;
            const unsigned char* g =
                (const unsigned char*)(gb + (size_t)(off0 + row) * ld + ts * 64) + kbs;
            gld_lds16(g, lb + q * 8192);
        }
    };
    auto LDA4 = [&](bf16x8* dst, int fmb, int kk, lds_u8* Ab) {
#pragma unroll
        for (int f = 0; f < 4; ++f) {
            int r = wm * 128 + (fmb + f) * 16 + lm;
            dst[f] = *(lds_cvec*)(Ab + r * 128 + ((kk * 64 + kg16) ^ swz));
        }
    };
    auto LDB4 = [&](bf16x8* dst, int kk, lds_u8* Bb) {
#pragma unroll
        for (int f = 0; f < 4; ++f) {
            int c = wn * 64 + f * 16 + lm;
            dst[f] = *(lds_cvec*)(Bb + c * 128 + ((kk * 64 + kg16) ^ swz));
        }
    };

    // swapped operands: D frag = C^T block (rows=N, cols=M)
#define MM16(a4, b4, mo)                                                        \
    do {                                                                        \
        __builtin_amdgcn_s_setprio(1);                                          \
        _Pragma("unroll")                                                       \
        for (int fm = 0; fm < 4; ++fm)                                          \
            _Pragma("unroll")                                                   \
            for (int fn = 0; fn < 4; ++fn)                                      \
                acc[(mo) + fm][fn] = __builtin_amdgcn_mfma_f32_16x16x32_bf16(   \
                    (b4)[fn], (a4)[fm], acc[(mo) + fm][fn], 0, 0, 0);           \
        __builtin_amdgcn_s_setprio(0);                                          \
    } while (0)

    // phase tail: drain own ds_reads (cheap: they overlapped the MFMAs), pin
    // so nothing crosses, then the single per-phase barrier. PHV2 also drains
    // vmem to 2 outstanding (buffer publish, per ledger above).
#define PHEND()                                                     \
    do {                                                            \
        asm volatile("s_waitcnt lgkmcnt(0)");                       \
        __builtin_amdgcn_sched_barrier(0);                          \
        __builtin_amdgcn_s_barrier();                               \
    } while (0)
#define PHEND_VM2()                                                 \
    do {                                                            \
        asm volatile("s_waitcnt vmcnt(2) lgkmcnt(0)");              \
        __builtin_amdgcn_sched_barrier(0);                          \
        __builtin_amdgcn_s_barrier();                               \
    } while (0)

    const int NT = Kdim >> 6;   // K-tiles of 64 (even, >= 8 here)
    const int NI = NT >> 1;

    // prologue: t0 {Bl,Bh,Al,Ah} -> buf0, t1 {Bl,Bh} -> buf1  (12 loads)
    STAGE(0, 1, 0, 0); STAGE(0, 1, 0, 1);
    STAGE(0, 0, 0, 0); STAGE(0, 0, 0, 1);
    STAGE(1, 1, 1, 0); STAGE(1, 1, 1, 1);
    asm volatile("s_waitcnt vmcnt(4)");      // t0 fully landed
    __builtin_amdgcn_s_barrier();

    bf16x8 a03[4], a47[4], b0[4], b1[4];
    // pre-read ph1 frags (tile 0, kk0, buf0)
    LDB4(b0, 0, B0); LDA4(a03, 0, 0, A0);

    for (int i = 0; i < NI; ++i) {
        const int t = 2 * i;
        const int t1s = t + 1;                       // always < NT
        const int t2s = (t + 2 < NT) ? t + 2 : NT - 1;
        const int t3s = (t + 3 < NT) ? t + 3 : NT - 1;

        // ph1
        STAGE(t1s, 0, 1, 0);
        LDA4(a47, 4, 0, A0);
        MM16(a03, b0, 0);
        PHEND();
        // ph2
        STAGE(t1s, 0, 1, 1);
        LDA4(a03, 0, 1, A0); LDB4(b1, 1, B0);
        MM16(a47, b0, 4);
        PHEND();
        // ph3  (publishes buf1 = tile t+1)
        STAGE(t2s, 1, 0, 0);
        LDA4(a47, 4, 1, A0);
        MM16(a03, b1, 0);
        PHEND_VM2();
        // ph4
        STAGE(t2s, 1, 0, 1);
        LDA4(a03, 0, 0, A1); LDB4(b0, 0, B1);
        MM16(a47, b1, 4);
        PHEND();
        // ph5
        STAGE(t2s, 0, 0, 0);
        LDA4(a47, 4, 0, A1);
        MM16(a03, b0, 0);
        PHEND();
        // ph6
        STAGE(t2s, 0, 0, 1);
        LDA4(a03, 0, 1, A1); LDB4(b1, 1, B1);
        MM16(a47, b0, 4);
        PHEND();
        // ph7  (publishes buf0 = tile t+2)
        STAGE(t3s, 1, 1, 0);
        LDA4(a47, 4, 1, A1);
        MM16(a03, b1, 0);
        PHEND_VM2();
        // ph8
        STAGE(t3s, 1, 1, 1);
        LDA4(a03, 0, 0, A0); LDB4(b0, 0, B0);   // next tile's ph1 frags
        MM16(a47, b1, 4);
        PHEND();
    }

    asm volatile("s_waitcnt vmcnt(0)");

    // ---- epilogue (swapped layout): frag (fm,fn):
    // row m = bm + wm*128 + fm*16 + lm ; cols n = bn + wn*64 + fn*16 + (lane>>4)*4
    const int hi4 = (lane >> 4) * 4;
#pragma unroll
    for (int fm = 0; fm < 8; ++fm) {
        const int gr = bm + wm * 128 + fm * 16 + lm;
#pragma unroll
        for (int fn = 0; fn < 4; ++fn) {
            const int gcn = bn + wn * 64 + fn * 16 + hi4;
            f32x4 v = acc[fm][fn];
            if (ACT) {
#pragma unroll
                for (int e = 0; e < 4; ++e) v[e] = fmaxf(v[e], 0.f) + 1.f;
            }
            if (SCALE) {
                float4 d4 = *(const float4*)&denb[gcn];
                v[0] *= 1.f / (d4.x + EPSF);
                v[1] *= 1.f / (d4.y + EPSF);
                v[2] *= 1.f / (d4.z + EPSF);
                v[3] *= 1.f / (d4.w + EPSF);
            }
            if (OUT_BF16) {
                ushort4 o;
                o.x = f2bf(v[0]); o.y = f2bf(v[1]); o.z = f2bf(v[2]); o.w = f2bf(v[3]);
                *(ushort4*)((unsigned short*)Cout + strideC * z + (size_t)gr * ldc + gcn) = o;
            } else {
                *(float4*)((float*)Cout + strideC * z + (size_t)gr * ldc + gcn) =
                    *(float4*)&v;
            }
        }
    }
#undef MM16
#undef PHEND
#undef PHEND_VM2
}

// ---------------------------------------------------------------------------
extern "C" void kernel_launch(void* const* d_in, const int* in_sizes, int n_in,
                              void* d_out, int out_size, void* d_ws, size_t ws_size,
                              hipStream_t stream)
{
    (void)in_sizes; (void)n_in; (void)out_size;
    const float* x  = (const float*)d_in[0];
    const float* Wq = (const float*)d_in[1];
    const float* Wk = (const float*)d_in[2];
    const float* Wv = (const float*)d_in[3];
    float* out = (float*)d_out;

    const size_t nx   = (size_t)Bb * Ss * Dd;
    const size_t nW   = (size_t)3 * Dd * Ff;
    const size_t nQKV = (size_t)Bb * Ss * Ff;
    const size_t nCtx = (size_t)Bb * Ff * Ff;
    const size_t nP   = (size_t)16 * Ff * Ff;   // split-K partials (bf16)

    unsigned short* xb   = (unsigned short*)d_ws;          // [B][S][D]
    unsigned short* WT   = xb + nx;                        // [3][F][D]
    unsigned short* Qb   = WT + nW;                        // [B][S][F] (den-scaled)
    unsigned short* KbT  = Qb + nQKV;                      // [B][F][S]
    unsigned short* VbT  = KbT + nQKV;                     // [B][F][S]
    unsigned short* ctxb = VbT + nQKV;                     // [B][F][F]
    float* den = (float*)(ctxb + nCtx);                    // [B][F]
    unsigned short* pctx = (unsigned short*)(den + (size_t)Bb * Ff); // [16][F][F]

    const size_t need_split =
        ((nx + nW + 3 * nQKV + nCtx + nP) * 2 + (size_t)Bb * Ff * 4);
    const bool do_split = ws_size >= need_split;

    cvt_x_kernel<<<dim3((int)(nx / 4 / 256)), 256, 0, stream>>>(x, xb, (int)(nx / 4));
    cvt_wT_kernel<<<dim3(Ff / 32, Dd / 32, 3), 256, 0, stream>>>(Wq, Wk, Wv, WT);

    // K^T[f][s] = relu1(WkT @ x^T): A=WTk [F][D], Bt=xb [S][D]
    gemm8<1, 0, 1, 0><<<dim3(Ss / 256, Ff / 256, Bb), 512, 0, stream>>>(
        WT + (size_t)1 * Dd * Ff, xb, KbT, nullptr,
        Dd, Dd, Ss, Dd, 0, (size_t)Ss * Dd, (size_t)Ff * Ss);

    // den[b][f] = sum_s K^T[f][s]
    den_kernel<<<dim3(Ff / 4, Bb), 256, 0, stream>>>(KbT, den);

    // Qs[s][f] = relu1(x @ Wq) / (den[f]+eps)
    gemm8<1, 1, 1, 0><<<dim3(Ff / 256, Ss / 256, Bb), 512, 0, stream>>>(
        xb, WT + (size_t)0 * Dd * Ff, Qb, den,
        Dd, Dd, Ff, Dd, (size_t)Ss * Dd, 0, (size_t)Ss * Ff);

    // V^T[g][s]
    gemm8<0, 0, 1, 0><<<dim3(Ss / 256, Ff / 256, Bb), 512, 0, stream>>>(
        WT + (size_t)2 * Dd * Ff, xb, VbT, nullptr,
        Dd, Dd, Ss, Dd, 0, (size_t)Ss * Dd, (size_t)Ff * Ss);

    // ctxRaw[f][g] = K^T V  (split-K=2 -> 256 blocks)
    if (do_split) {
        gemm8<0, 0, 1, 1><<<dim3(Ff / 256, Ff / 256, 2 * Bb), 512, 0, stream>>>(
            KbT, VbT, pctx, nullptr,
            Ss, Ss, Ff, Ss / 2, (size_t)Ff * Ss, (size_t)Ff * Ss, (size_t)Ff * Ff);
        add_ctx_kernel<<<dim3(Ff * Ff / 8 / 256, Bb), 256, 0, stream>>>(pctx, ctxb);
    } else {
        gemm8<0, 0, 1, 0><<<dim3(Ff / 256, Ff / 256, Bb), 512, 0, stream>>>(
            KbT, VbT, ctxb, nullptr,
            Ss, Ss, Ff, Ss, (size_t)Ff * Ss, (size_t)Ff * Ss, (size_t)Ff * Ff);
    }

    // out[f][s] = ctxRaw @ Qs^T (fp32 out)
    gemm8<0, 0, 0, 0><<<dim3(Ss / 256, Ff / 256, Bb), 512, 0, stream>>>(
        ctxb, Qb, out, nullptr,
        Ff, Ff, Ss, Ff, (size_t)Ff * Ff, (size_t)Ss * Ff, (size_t)Ff * Ss);
}